// Round 12
// baseline (162.554 us; speedup 1.0000x reference)
//
#include <hip/hip_runtime.h>
#include <math.h>

#define NN 4096
#define MM 32
#define LOG2F_ 0.69314718055994530942f

typedef __attribute__((ext_vector_type(8))) short short8;
typedef __attribute__((ext_vector_type(4))) float f32x4;

__device__ __forceinline__ float ssp_fast(float x) {
    float sp = (x > 20.0f) ? x : __logf(1.0f + __expf(x));
    return sp - LOG2F_;
}

// float -> bf16 bits, round-to-nearest-even
__device__ __forceinline__ short f2bf(float x) {
    unsigned u = __float_as_uint(x);
    unsigned r = (u + 0x7FFFu + ((u >> 16) & 1u)) >> 16;
    return (short)r;
}
__device__ __forceinline__ float bf2f(short s) {
    return __uint_as_float(((unsigned)(unsigned short)s) << 16);
}

// K1: pre = ielin(feat, w_pre0, w_pre1) via MFMA, 8 nodes/block.
// Weight->bf16^T conversion spread across all blocks (<=1 elem/thread).
__global__ __launch_bounds__(256) void pre_kernel(
    const float* __restrict__ feat, const float* __restrict__ w0,
    const float* __restrict__ w1, float* __restrict__ pre_t,
    const float* __restrict__ w_f1, const float* __restrict__ w_f2,
    const float* __restrict__ w_a0, const float* __restrict__ w_a1,
    const float* __restrict__ w_b0, const float* __restrict__ w_b1,
    short* __restrict__ w1t, short* __restrict__ w2t,
    short* __restrict__ w_a0t, short* __restrict__ w_a1t,
    short* __restrict__ w_b0t, short* __restrict__ w_b1t)
{
    int t = threadIdx.x;
    int base = blockIdx.x * 8;
    int lane = t & 63, wave = t >> 6, q = lane >> 4, nn = lane & 15;

    // distributed weight transpose+convert: gid in [0, 34816)
    {
        int gid = blockIdx.x * 256 + t;
        if (gid < 2048) {
            int n = gid >> 5, k = gid & 31;
            w1t[gid] = (k < 16) ? f2bf(w_f1[k * 64 + n]) : (short)0;
        } else if (gid < 6144) {
            int idx = gid - 2048; int n = idx >> 6, k = idx & 63;
            w2t[idx] = f2bf(w_f2[k * 64 + n]);
        } else if (gid < 10240) {
            int idx = gid - 6144; int n = idx >> 6, k = idx & 63;
            w_b0t[idx] = f2bf(w_b0[k * 64 + n]);
        } else if (gid < 14336) {
            int idx = gid - 10240; int n = idx >> 6, k = idx & 63;
            w_b1t[idx] = f2bf(w_b1[k * 64 + n]);
        } else if (gid < 22528) {
            int idx = gid - 14336; int n = idx >> 7, k = idx & 127;
            w_a0t[idx] = f2bf(w_a0[k * 64 + n]);
        } else if (gid < 34816) {
            int idx = gid - 22528; int n = idx / 192, k = idx - n * 192;
            w_a1t[idx] = f2bf(w_a1[k * 64 + n]);
        }
    }

    __shared__ __align__(16) short s_a0[16 * 72];
    __shared__ __align__(16) short s_a1[2][16 * 72];
    __shared__ __align__(16) short s_w0[64 * 72];
    __shared__ __align__(16) short s_w1[64 * 72];
    __shared__ __align__(16) float s_po[8][256];

    for (int idx = t; idx < 512; idx += 256) {
        int r = 8 + (idx >> 6), k = idx & 63;
        s_a0[r * 72 + k] = 0;
        s_a1[1][r * 72 + k] = 0;
    }
    #pragma unroll 4
    for (int kk = 0; kk < 16; ++kk) {
        int k = wave * 16 + kk;
        s_w0[lane * 72 + k] = f2bf(w0[k * 64 + lane]);
        s_w1[lane * 72 + k] = f2bf(w1[k * 64 + lane]);
    }
    {
        const float4* f4 = (const float4*)(feat + (size_t)base * 256);
        #pragma unroll
        for (int rep = 0; rep < 2; ++rep) {
            int idx = t + rep * 256;
            float4 v = f4[idx];
            int node = idx >> 6, c = (idx & 63) * 4;
            short* dst;
            if (c < 64) {
                dst = &s_a0[node * 72 + c];
            } else {
                int mm = (c >> 6) - 1, ch = c & 63;
                int row = node * 3 + mm;
                dst = &s_a1[row >> 4][(row & 15) * 72 + ch];
            }
            dst[0] = f2bf(v.x); dst[1] = f2bf(v.y);
            dst[2] = f2bf(v.z); dst[3] = f2bf(v.w);
        }
    }
    __syncthreads();

    short8 bw0[2], bw1[2];
    #pragma unroll
    for (int kc = 0; kc < 2; ++kc) {
        bw0[kc] = *(const short8*)&s_w0[(16 * wave + nn) * 72 + kc * 32 + q * 8];
        bw1[kc] = *(const short8*)&s_w1[(16 * wave + nn) * 72 + kc * 32 + q * 8];
    }
    {
        f32x4 acc = {0.f, 0.f, 0.f, 0.f};
        #pragma unroll
        for (int kc = 0; kc < 2; ++kc) {
            short8 a = *(const short8*)&s_a0[nn * 72 + kc * 32 + q * 8];
            acc = __builtin_amdgcn_mfma_f32_16x16x32_bf16(a, bw0[kc], acc, 0, 0, 0);
        }
        if (q < 2) {
            #pragma unroll
            for (int r = 0; r < 4; ++r)
                s_po[4 * q + r][(16 * wave + nn) * 4 + 0] = acc[r];
        }
    }
    #pragma unroll
    for (int tile = 0; tile < 2; ++tile) {
        f32x4 acc = {0.f, 0.f, 0.f, 0.f};
        #pragma unroll
        for (int kc = 0; kc < 2; ++kc) {
            short8 a = *(const short8*)&s_a1[tile][nn * 72 + kc * 32 + q * 8];
            acc = __builtin_amdgcn_mfma_f32_16x16x32_bf16(a, bw1[kc], acc, 0, 0, 0);
        }
        #pragma unroll
        for (int r = 0; r < 4; ++r) {
            int row = tile * 16 + 4 * q + r;
            if (row < 24) {
                unsigned node = (unsigned)row / 3u;
                int mm = row - (int)node * 3;
                s_po[node][(16 * wave + nn) * 4 + 1 + mm] = acc[r];
            }
        }
    }
    __syncthreads();

    #pragma unroll
    for (int rep = 0; rep < 2; ++rep) {
        int idx = t + rep * 256;
        int node = idx >> 6, c4 = idx & 63;
        *(float4*)&pre_t[(size_t)(base + node) * 256 + c4 * 4] =
            *(const float4*)&s_po[node][c4 * 4];
    }
}

// K2: ONE node per block (4096 blocks). LDS 19.2 KB -> 8 blocks/CU (100%
// wave occupancy). Register geometry (8-way redundant per wave), prefetched
// gather, MFMA radial MLP, VALU coupling, MFMA P5.
__global__ __launch_bounds__(256, 8) void edge_kernel(
    const float* __restrict__ xyz, const float* __restrict__ feat,
    const float* __restrict__ pre_t,
    const short* __restrict__ w1t_g, const short* __restrict__ w2t_g,
    const short* __restrict__ w_a0t, const short* __restrict__ w_a1t,
    const short* __restrict__ w_b0t, const short* __restrict__ w_b1t,
    const int* __restrict__ src_idx, const int* __restrict__ edge_mask,
    float* __restrict__ out)
{
    int i = blockIdx.x;            // one node per block
    int t = threadIdx.x;
    int lane = t & 63;
    int wave = t >> 6;
    int q = lane >> 4;
    int nn = lane & 15;

    __shared__ __align__(16) char s_ra[2816];   // rbf(2560) -> agg(2816)
    __shared__ __align__(16) char s_u[16384];   // h+f -> P5 overlays
    short* s_rbf = (short*)s_ra;                // 32 x 40
    float* s_agg = (float*)s_ra;                // 704
    short* s_h = (short*)s_u;                   // 32 x 72
    short* s_f = (short*)(s_u + 4608);          // 32 x 72

    short8 b1   = *(const short8*)&w1t_g[(16 * wave + nn) * 32 + q * 8];
    short8 b2_0 = *(const short8*)&w2t_g[(16 * wave + nn) * 64 + q * 8];
    short8 b2_1 = *(const short8*)&w2t_g[(16 * wave + nn) * 64 + 32 + q * 8];

    // zero rbf K-pad cols 16..31
    for (int idx = t; idx < 512; idx += 256) {
        int e = idx >> 4, k = 16 + (idx & 15);
        s_rbf[e * 40 + k] = 0;
    }

    // geometry: edge = 8*wave + (lane&7), 8-way redundant per wave
    int e_g = 8 * wave + (lane & 7);
    int j = src_idx[i * MM + e_g];
    float msk = (float)edge_mask[i * MM + e_g];
    float r0 = xyz[j * 3 + 0] - xyz[i * 3 + 0];
    float r1 = xyz[j * 3 + 1] - xyz[i * 3 + 1];
    float r2 = xyz[j * 3 + 2] - xyz[i * 3 + 2];
    float d = sqrtf(r0 * r0 + r1 * r1 + r2 * r2);
    float inv_d = 1.0f / d;
    float x = d * 0.2f;
    float env = 0.f;
    if (x < 1.f) {
        float x3 = x * x * x;
        env = 1.f - 10.f * x3 + 15.f * x3 * x - 6.f * x3 * x * x;
    }
    float sc = env * inv_d;
    float ry = r1 * inv_d, rz = r2 * inv_d, rx = r0 * inv_d;

    // prefetch first 4 of the wave's 8 edges
    float4 pv[2][4];
    #pragma unroll
    for (int u = 0; u < 4; ++u) {
        int ju = __shfl(j, u, 64);
        pv[0][u] = ((const float4*)pre_t)[(size_t)ju * 64 + lane];
    }

    // sins: 2 per lane (own edge, k = 2*(lane>>3) + {0,1})
    {
        int kb = 2 * (lane >> 3);
        s_rbf[e_g * 40 + kb]     = f2bf(__sinf(x * (float)kb) * sc);
        s_rbf[e_g * 40 + kb + 1] = f2bf(__sinf(x * (float)(kb + 1)) * sc);
    }
    __syncthreads();                                              // B1

    // P2: h = ssp(rbf @ w1), M=32 (2 m-tiles)
    {
        f32x4 z = {0.f, 0.f, 0.f, 0.f};
        #pragma unroll
        for (int mt = 0; mt < 2; ++mt) {
            short8 a = *(const short8*)&s_rbf[(16 * mt + nn) * 40 + q * 8];
            f32x4 h = __builtin_amdgcn_mfma_f32_16x16x32_bf16(a, b1, z, 0, 0, 0);
            #pragma unroll
            for (int r = 0; r < 4; ++r)
                s_h[(16 * mt + 4 * q + r) * 72 + 16 * wave + nn] = f2bf(ssp_fast(h[r]));
        }
    }
    __syncthreads();                                              // B2

    // zero agg (rbf dead) + P3: fr = h @ w2
    for (int k = t; k < 704; k += 256) s_agg[k] = 0.f;
    {
        #pragma unroll
        for (int mt = 0; mt < 2; ++mt) {
            f32x4 acc = {0.f, 0.f, 0.f, 0.f};
            short8 a0 = *(const short8*)&s_h[(16 * mt + nn) * 72 + q * 8];
            acc = __builtin_amdgcn_mfma_f32_16x16x32_bf16(a0, b2_0, acc, 0, 0, 0);
            short8 a1 = *(const short8*)&s_h[(16 * mt + nn) * 72 + 32 + q * 8];
            acc = __builtin_amdgcn_mfma_f32_16x16x32_bf16(a1, b2_1, acc, 0, 0, 0);
            #pragma unroll
            for (int r = 0; r < 4; ++r)
                s_f[(16 * mt + 4 * q + r) * 72 + 16 * wave + nn] = f2bf(acc[r]);
        }
    }
    __syncthreads();                                              // B3

    // P4: coupling; wave -> its 8 edges; lane == channel
    {
        int ebase = wave * 8;
        float acc0a = 0.f, acc0b = 0.f;
        float P01[3] = {0.f, 0.f, 0.f};
        float P10[3] = {0.f, 0.f, 0.f};
        float P11[3] = {0.f, 0.f, 0.f};

        // load second group of 4
        #pragma unroll
        for (int u = 0; u < 4; ++u) {
            int jn = __shfl(j, 4 + u, 64);
            pv[1][u] = ((const float4*)pre_t)[(size_t)jn * 64 + lane];
        }

        #pragma unroll
        for (int g = 0; g < 2; ++g) {
            #pragma unroll
            for (int u = 0; u < 4; ++u) {
                int el = g * 4 + u;
                float ryu = __shfl(ry, el, 64);
                float rzu = __shfl(rz, el, 64);
                float rxu = __shfl(rx, el, 64);
                float msku = __shfl(msk, el, 64);
                float f = bf2f(s_f[(ebase + el) * 72 + lane]) * msku;
                float a0 = pv[g][u].x, a1y = pv[g][u].y;
                float a1z = pv[g][u].z, a1x = pv[g][u].w;

                float a0f = a0 * f;
                acc0a += a0f;
                acc0b = fmaf(f, a1y * ryu + a1z * rzu + a1x * rxu, acc0b);
                P01[0] = fmaf(a0f, ryu, P01[0]);
                P01[1] = fmaf(a0f, rzu, P01[1]);
                P01[2] = fmaf(a0f, rxu, P01[2]);
                P10[0] = fmaf(a1y, f, P10[0]);
                P10[1] = fmaf(a1z, f, P10[1]);
                P10[2] = fmaf(a1x, f, P10[2]);
                P11[0] = fmaf(a1z * rxu - a1x * rzu, f, P11[0]);  // cy
                P11[1] = fmaf(a1x * ryu - a1y * rxu, f, P11[1]);  // cz
                P11[2] = fmaf(a1y * rzu - a1z * ryu, f, P11[2]);  // cx
            }
        }

        atomicAdd(&s_agg[lane], acc0a);
        atomicAdd(&s_agg[64 + lane], acc0b);
        #pragma unroll
        for (int m = 0; m < 3; ++m) {
            atomicAdd(&s_agg[128 + m * 192 + lane], P01[m]);
            atomicAdd(&s_agg[128 + m * 192 + 64 + lane], P10[m]);
            atomicAdd(&s_agg[128 + m * 192 + 128 + lane], P11[m]);
        }
    }
    __syncthreads();                                              // B4

    // P5 overlays over s_u (h/f dead). Garbage A rows harmless: C row r
    // depends only on A row r, and we never read those C rows.
    short* l0a    = (short*)s_u;              // 16x136 (row 0 valid)
    short* l1a    = (short*)(s_u + 4352);     // 16x200 (rows 0-2 valid)
    float* s_cout = (float*)(s_u + 10752);    // 256 fp32
    short* g0t    = (short*)(s_u + 11776);    // 16x72 (row 0 valid)
    short* g1t    = (short*)(s_u + 14080);    // 16x72 (rows 0-2 valid)

    // pack agg -> bf16 A tiles
    if (t < 128) l0a[t] = f2bf(s_agg[t]);
    for (int idx = t; idx < 576; idx += 256) {
        int m = idx / 192, c = idx - m * 192;
        l1a[m * 200 + c] = f2bf(s_agg[128 + m * 192 + c]);
    }
    __syncthreads();                                              // B5

    // P5a: cout = ielin(agg, w_a) via MFMA
    int col = 16 * wave + nn;
    {
        f32x4 acc0 = {0.f, 0.f, 0.f, 0.f};
        #pragma unroll
        for (int kc = 0; kc < 4; ++kc) {
            short8 b = *(const short8*)&w_a0t[col * 128 + kc * 32 + q * 8];
            short8 a = *(const short8*)&l0a[nn * 136 + kc * 32 + q * 8];
            acc0 = __builtin_amdgcn_mfma_f32_16x16x32_bf16(a, b, acc0, 0, 0, 0);
        }
        if (q == 0) s_cout[col] = acc0[0];

        f32x4 acc1 = {0.f, 0.f, 0.f, 0.f};
        #pragma unroll
        for (int kc = 0; kc < 6; ++kc) {
            short8 b = *(const short8*)&w_a1t[col * 192 + kc * 32 + q * 8];
            short8 a = *(const short8*)&l1a[nn * 200 + kc * 32 + q * 8];
            acc1 = __builtin_amdgcn_mfma_f32_16x16x32_bf16(a, b, acc1, 0, 0, 0);
        }
        if (q == 0) {
            #pragma unroll
            for (int r = 0; r < 3; ++r)
                s_cout[64 + r * 64 + col] = acc1[r];
        }
    }
    __syncthreads();                                              // B6

    // gate -> bf16 gated A-tiles
    {
        float v = s_cout[t];
        float g;
        if (wave == 0) {
            g = ssp_fast(v);
        } else {
            float c0 = s_cout[64 + lane];
            float c1 = s_cout[128 + lane];
            float c2 = s_cout[192 + lane];
            g = ssp_fast(sqrtf(fmaf(c0, c0, fmaf(c1, c1, fmaf(c2, c2, 1e-12f)))));
        }
        float gv = v * g;
        if (wave == 0) g0t[lane] = f2bf(gv);
        else           g1t[(wave - 1) * 72 + lane] = f2bf(gv);
    }
    __syncthreads();                                              // B7

    // P5b: out = feat + ielin(gated, w_b) via MFMA
    {
        f32x4 acc0 = {0.f, 0.f, 0.f, 0.f};
        #pragma unroll
        for (int kc = 0; kc < 2; ++kc) {
            short8 b = *(const short8*)&w_b0t[col * 64 + kc * 32 + q * 8];
            short8 a = *(const short8*)&g0t[nn * 72 + kc * 32 + q * 8];
            acc0 = __builtin_amdgcn_mfma_f32_16x16x32_bf16(a, b, acc0, 0, 0, 0);
        }
        if (q == 0) {
            size_t o = (size_t)i * 256 + col;
            out[o] = feat[o] + acc0[0];
        }
        f32x4 acc1 = {0.f, 0.f, 0.f, 0.f};
        #pragma unroll
        for (int kc = 0; kc < 2; ++kc) {
            short8 b = *(const short8*)&w_b1t[col * 64 + kc * 32 + q * 8];
            short8 a = *(const short8*)&g1t[nn * 72 + kc * 32 + q * 8];
            acc1 = __builtin_amdgcn_mfma_f32_16x16x32_bf16(a, b, acc1, 0, 0, 0);
        }
        if (q == 0) {
            #pragma unroll
            for (int r = 0; r < 3; ++r) {
                size_t o = (size_t)i * 256 + 64 + r * 64 + col;
                out[o] = feat[o] + acc1[r];
            }
        }
    }
}

extern "C" void kernel_launch(void* const* d_in, const int* in_sizes, int n_in,
                              void* d_out, int out_size, void* d_ws, size_t ws_size,
                              hipStream_t stream) {
    const float* xyz     = (const float*)d_in[0];
    const float* feat    = (const float*)d_in[1];
    const float* w_f1    = (const float*)d_in[2];
    const float* w_f2    = (const float*)d_in[3];
    const float* w_pre0  = (const float*)d_in[4];
    const float* w_pre1  = (const float*)d_in[5];
    const float* w_a0    = (const float*)d_in[6];
    const float* w_a1    = (const float*)d_in[7];
    const float* w_b0    = (const float*)d_in[8];
    const float* w_b1    = (const float*)d_in[9];
    const int* src_idx   = (const int*)d_in[10];
    const int* edge_mask = (const int*)d_in[11];
    float* out = (float*)d_out;

    char* ws = (char*)d_ws;
    float* pre_t = (float*)ws;                          // 4 MB
    short* w1t   = (short*)(ws + 4194304);              // 4 KB
    short* w2t   = (short*)(ws + 4194304 + 4096);       // 8 KB
    short* w_a0t = (short*)(ws + 4194304 + 12288);      // 16 KB
    short* w_a1t = (short*)(ws + 4194304 + 28672);      // 24 KB
    short* w_b0t = (short*)(ws + 4194304 + 53248);      // 8 KB
    short* w_b1t = (short*)(ws + 4194304 + 61440);      // 8 KB

    pre_kernel<<<NN / 8, 256, 0, stream>>>(feat, w_pre0, w_pre1, pre_t,
                                           w_f1, w_f2, w_a0, w_a1, w_b0, w_b1,
                                           w1t, w2t, w_a0t, w_a1t, w_b0t, w_b1t);
    edge_kernel<<<NN, 256, 0, stream>>>(xyz, feat, pre_t, w1t, w2t,
                                        w_a0t, w_a1t, w_b0t, w_b1t,
                                        src_idx, edge_mask, out);
}

// Round 13
// 135.913 us; speedup vs baseline: 1.1960x; 1.1960x over previous
//
#include <hip/hip_runtime.h>
#include <math.h>

#define NN 4096
#define MM 32
#define LOG2F_ 0.69314718055994530942f

typedef __attribute__((ext_vector_type(8))) short short8;
typedef __attribute__((ext_vector_type(4))) float f32x4;

__device__ __forceinline__ float ssp_fast(float x) {
    float sp = (x > 20.0f) ? x : __logf(1.0f + __expf(x));
    return sp - LOG2F_;
}

// float -> bf16 bits, round-to-nearest-even
__device__ __forceinline__ short f2bf(float x) {
    unsigned u = __float_as_uint(x);
    unsigned r = (u + 0x7FFFu + ((u >> 16) & 1u)) >> 16;
    return (short)r;
}
__device__ __forceinline__ float bf2f(short s) {
    return __uint_as_float(((unsigned)(unsigned short)s) << 16);
}

// K1: pre = ielin(feat, w_pre0, w_pre1) via MFMA, 8 nodes/block.
// Weight->bf16^T conversion spread across all blocks (<=1 elem/thread).
__global__ __launch_bounds__(256) void pre_kernel(
    const float* __restrict__ feat, const float* __restrict__ w0,
    const float* __restrict__ w1, float* __restrict__ pre_t,
    const float* __restrict__ w_f1, const float* __restrict__ w_f2,
    const float* __restrict__ w_a0, const float* __restrict__ w_a1,
    const float* __restrict__ w_b0, const float* __restrict__ w_b1,
    short* __restrict__ w1t, short* __restrict__ w2t,
    short* __restrict__ w_a0t, short* __restrict__ w_a1t,
    short* __restrict__ w_b0t, short* __restrict__ w_b1t)
{
    int t = threadIdx.x;
    int base = blockIdx.x * 8;
    int lane = t & 63, wave = t >> 6, q = lane >> 4, nn = lane & 15;

    // distributed weight transpose+convert: gid in [0, 34816)
    {
        int gid = blockIdx.x * 256 + t;
        if (gid < 2048) {
            int n = gid >> 5, k = gid & 31;
            w1t[gid] = (k < 16) ? f2bf(w_f1[k * 64 + n]) : (short)0;
        } else if (gid < 6144) {
            int idx = gid - 2048; int n = idx >> 6, k = idx & 63;
            w2t[idx] = f2bf(w_f2[k * 64 + n]);
        } else if (gid < 10240) {
            int idx = gid - 6144; int n = idx >> 6, k = idx & 63;
            w_b0t[idx] = f2bf(w_b0[k * 64 + n]);
        } else if (gid < 14336) {
            int idx = gid - 10240; int n = idx >> 6, k = idx & 63;
            w_b1t[idx] = f2bf(w_b1[k * 64 + n]);
        } else if (gid < 22528) {
            int idx = gid - 14336; int n = idx >> 7, k = idx & 127;
            w_a0t[idx] = f2bf(w_a0[k * 64 + n]);
        } else if (gid < 34816) {
            int idx = gid - 22528; int n = idx / 192, k = idx - n * 192;
            w_a1t[idx] = f2bf(w_a1[k * 64 + n]);
        }
    }

    __shared__ __align__(16) short s_a0[16 * 72];
    __shared__ __align__(16) short s_a1[2][16 * 72];
    __shared__ __align__(16) short s_w0[64 * 72];
    __shared__ __align__(16) short s_w1[64 * 72];
    __shared__ __align__(16) float s_po[8][256];

    for (int idx = t; idx < 512; idx += 256) {
        int r = 8 + (idx >> 6), k = idx & 63;
        s_a0[r * 72 + k] = 0;
        s_a1[1][r * 72 + k] = 0;
    }
    #pragma unroll 4
    for (int kk = 0; kk < 16; ++kk) {
        int k = wave * 16 + kk;
        s_w0[lane * 72 + k] = f2bf(w0[k * 64 + lane]);
        s_w1[lane * 72 + k] = f2bf(w1[k * 64 + lane]);
    }
    {
        const float4* f4 = (const float4*)(feat + (size_t)base * 256);
        #pragma unroll
        for (int rep = 0; rep < 2; ++rep) {
            int idx = t + rep * 256;
            float4 v = f4[idx];
            int node = idx >> 6, c = (idx & 63) * 4;
            short* dst;
            if (c < 64) {
                dst = &s_a0[node * 72 + c];
            } else {
                int mm = (c >> 6) - 1, ch = c & 63;
                int row = node * 3 + mm;
                dst = &s_a1[row >> 4][(row & 15) * 72 + ch];
            }
            dst[0] = f2bf(v.x); dst[1] = f2bf(v.y);
            dst[2] = f2bf(v.z); dst[3] = f2bf(v.w);
        }
    }
    __syncthreads();

    short8 bw0[2], bw1[2];
    #pragma unroll
    for (int kc = 0; kc < 2; ++kc) {
        bw0[kc] = *(const short8*)&s_w0[(16 * wave + nn) * 72 + kc * 32 + q * 8];
        bw1[kc] = *(const short8*)&s_w1[(16 * wave + nn) * 72 + kc * 32 + q * 8];
    }
    {
        f32x4 acc = {0.f, 0.f, 0.f, 0.f};
        #pragma unroll
        for (int kc = 0; kc < 2; ++kc) {
            short8 a = *(const short8*)&s_a0[nn * 72 + kc * 32 + q * 8];
            acc = __builtin_amdgcn_mfma_f32_16x16x32_bf16(a, bw0[kc], acc, 0, 0, 0);
        }
        if (q < 2) {
            #pragma unroll
            for (int r = 0; r < 4; ++r)
                s_po[4 * q + r][(16 * wave + nn) * 4 + 0] = acc[r];
        }
    }
    #pragma unroll
    for (int tile = 0; tile < 2; ++tile) {
        f32x4 acc = {0.f, 0.f, 0.f, 0.f};
        #pragma unroll
        for (int kc = 0; kc < 2; ++kc) {
            short8 a = *(const short8*)&s_a1[tile][nn * 72 + kc * 32 + q * 8];
            acc = __builtin_amdgcn_mfma_f32_16x16x32_bf16(a, bw1[kc], acc, 0, 0, 0);
        }
        #pragma unroll
        for (int r = 0; r < 4; ++r) {
            int row = tile * 16 + 4 * q + r;
            if (row < 24) {
                unsigned node = (unsigned)row / 3u;
                int mm = row - (int)node * 3;
                s_po[node][(16 * wave + nn) * 4 + 1 + mm] = acc[r];
            }
        }
    }
    __syncthreads();

    #pragma unroll
    for (int rep = 0; rep < 2; ++rep) {
        int idx = t + rep * 256;
        int node = idx >> 6, c4 = idx & 63;
        *(float4*)&pre_t[(size_t)(base + node) * 256 + c4 * 4] =
            *(const float4*)&s_po[node][c4 * 4];
    }
}

// K2: FOUR nodes per block (1024 blocks), two radial passes of 2 nodes each
// (R11's proven 64-edge pipeline), then ONE shared MFMA P5 for all 4 nodes.
// Per-node fixed cost (P5 MFMAs + weight fragments) halves vs the 2-node
// version. LDS 34.8 KB -> 4 blocks/CU.
__global__ __launch_bounds__(256, 4) void edge_kernel(
    const float* __restrict__ xyz, const float* __restrict__ feat,
    const float* __restrict__ pre_t,
    const short* __restrict__ w1t_g, const short* __restrict__ w2t_g,
    const short* __restrict__ w_a0t, const short* __restrict__ w_a1t,
    const short* __restrict__ w_b0t, const short* __restrict__ w_b1t,
    const int* __restrict__ src_idx, const int* __restrict__ edge_mask,
    float* __restrict__ out)
{
    int i0 = blockIdx.x * 4;
    int t = threadIdx.x;
    int lane = t & 63;
    int wave = t >> 6;
    int q = lane >> 4;
    int nn = lane & 15;

    __shared__ __align__(16) char s_rr[5120];    // rbf 64x40; later cout 4x256
    __shared__ __align__(16) char s_u[18432];    // h + f; later P5 A-tiles
    __shared__ __align__(16) float s_agg[4 * 704];  // survives both passes
    short* s_rbf = (short*)s_rr;
    short* s_h = (short*)s_u;
    short* s_f = (short*)(s_u + 9216);

    // radial B-fragments: loaded once, reused in both passes
    short8 b1   = *(const short8*)&w1t_g[(16 * wave + nn) * 32 + q * 8];
    short8 b2_0 = *(const short8*)&w2t_g[(16 * wave + nn) * 64 + q * 8];
    short8 b2_1 = *(const short8*)&w2t_g[(16 * wave + nn) * 64 + 32 + q * 8];

    for (int k = t; k < 2816; k += 256) s_agg[k] = 0.f;
    for (int idx = t; idx < 1024; idx += 256) {   // rbf K-pad cols 16..31
        int e = idx >> 4, k = 16 + (idx & 15);
        s_rbf[e * 40 + k] = 0;
    }

    #pragma unroll 1
    for (int p = 0; p < 2; ++p) {
        // geometry: every lane computes its wave's edge (lane&15)
        int e_g = 16 * wave + (lane & 15);
        int i_node = i0 + 2 * p + (e_g >> 5);
        int edge = e_g & 31;
        int j = src_idx[i_node * MM + edge];
        float msk = (float)edge_mask[i_node * MM + edge];
        float r0 = xyz[j * 3 + 0] - xyz[i_node * 3 + 0];
        float r1 = xyz[j * 3 + 1] - xyz[i_node * 3 + 1];
        float r2 = xyz[j * 3 + 2] - xyz[i_node * 3 + 2];
        float d = sqrtf(r0 * r0 + r1 * r1 + r2 * r2);
        float inv_d = 1.0f / d;
        float x = d * 0.2f;
        float env = 0.f;
        if (x < 1.f) {
            float x3 = x * x * x;
            env = 1.f - 10.f * x3 + 15.f * x3 * x - 6.f * x3 * x * x;
        }
        float sc = env * inv_d;
        float ry = r1 * inv_d, rz = r2 * inv_d, rx = r0 * inv_d;

        // prefetch first 8 of the wave's 16 edges
        float4 pv[2][4];
        #pragma unroll
        for (int u = 0; u < 4; ++u) {
            int ju = __shfl(j, u, 64);
            pv[0][u] = ((const float4*)pre_t)[(size_t)ju * 64 + lane];
        }
        #pragma unroll
        for (int u = 0; u < 4; ++u) {
            int ju = __shfl(j, 4 + u, 64);
            pv[1][u] = ((const float4*)pre_t)[(size_t)ju * 64 + lane];
        }

        // sins: 4 per lane (own edge)
        {
            float kbase = (float)(4 * (lane >> 4));
            #pragma unroll
            for (int jj = 0; jj < 4; ++jj)
                s_rbf[e_g * 40 + 4 * (lane >> 4) + jj] =
                    f2bf(__sinf(x * (kbase + (float)jj)) * sc);
        }
        __syncthreads();                                          // B1

        // P2: h = ssp(rbf @ w1)
        {
            f32x4 z = {0.f, 0.f, 0.f, 0.f};
            #pragma unroll
            for (int mt = 0; mt < 4; ++mt) {
                short8 a = *(const short8*)&s_rbf[(16 * mt + nn) * 40 + q * 8];
                f32x4 h = __builtin_amdgcn_mfma_f32_16x16x32_bf16(a, b1, z, 0, 0, 0);
                #pragma unroll
                for (int r = 0; r < 4; ++r)
                    s_h[(16 * mt + 4 * q + r) * 72 + 16 * wave + nn] = f2bf(ssp_fast(h[r]));
            }
        }
        __syncthreads();                                          // B2

        // P3: fr = h @ w2
        {
            #pragma unroll
            for (int mt = 0; mt < 4; ++mt) {
                f32x4 acc = {0.f, 0.f, 0.f, 0.f};
                short8 a0 = *(const short8*)&s_h[(16 * mt + nn) * 72 + q * 8];
                acc = __builtin_amdgcn_mfma_f32_16x16x32_bf16(a0, b2_0, acc, 0, 0, 0);
                short8 a1 = *(const short8*)&s_h[(16 * mt + nn) * 72 + 32 + q * 8];
                acc = __builtin_amdgcn_mfma_f32_16x16x32_bf16(a1, b2_1, acc, 0, 0, 0);
                #pragma unroll
                for (int r = 0; r < 4; ++r)
                    s_f[(16 * mt + 4 * q + r) * 72 + 16 * wave + nn] = f2bf(acc[r]);
            }
        }
        __syncthreads();                                          // B3

        // P4: coupling; wave -> its 16 edges; lane == channel
        {
            int ebase = wave * 16;
            float acc0a = 0.f, acc0b = 0.f;
            float P01[3] = {0.f, 0.f, 0.f};
            float P10[3] = {0.f, 0.f, 0.f};
            float P11[3] = {0.f, 0.f, 0.f};

            #pragma unroll
            for (int g = 0; g < 4; ++g) {
                float4 nx[4];
                if (g < 2) {
                    #pragma unroll
                    for (int u = 0; u < 4; ++u) {
                        int jn = __shfl(j, (g + 2) * 4 + u, 64);
                        nx[u] = ((const float4*)pre_t)[(size_t)jn * 64 + lane];
                    }
                }
                #pragma unroll
                for (int u = 0; u < 4; ++u) {
                    int el = g * 4 + u;
                    float ryu = __shfl(ry, el, 64);
                    float rzu = __shfl(rz, el, 64);
                    float rxu = __shfl(rx, el, 64);
                    float msku = __shfl(msk, el, 64);
                    float f = bf2f(s_f[(ebase + el) * 72 + lane]) * msku;
                    float a0 = pv[g & 1][u].x, a1y = pv[g & 1][u].y;
                    float a1z = pv[g & 1][u].z, a1x = pv[g & 1][u].w;

                    float a0f = a0 * f;
                    acc0a += a0f;
                    acc0b = fmaf(f, a1y * ryu + a1z * rzu + a1x * rxu, acc0b);
                    P01[0] = fmaf(a0f, ryu, P01[0]);
                    P01[1] = fmaf(a0f, rzu, P01[1]);
                    P01[2] = fmaf(a0f, rxu, P01[2]);
                    P10[0] = fmaf(a1y, f, P10[0]);
                    P10[1] = fmaf(a1z, f, P10[1]);
                    P10[2] = fmaf(a1x, f, P10[2]);
                    P11[0] = fmaf(a1z * rxu - a1x * rzu, f, P11[0]);  // cy
                    P11[1] = fmaf(a1x * ryu - a1y * rxu, f, P11[1]);  // cz
                    P11[2] = fmaf(a1y * rzu - a1z * ryu, f, P11[2]);  // cx
                }
                if (g < 2) {
                    #pragma unroll
                    for (int u = 0; u < 4; ++u) pv[g & 1][u] = nx[u];
                }
            }

            float* agg = &s_agg[(2 * p + (wave >> 1)) * 704];
            atomicAdd(&agg[lane], acc0a);
            atomicAdd(&agg[64 + lane], acc0b);
            #pragma unroll
            for (int m = 0; m < 3; ++m) {
                atomicAdd(&agg[128 + m * 192 + lane], P01[m]);
                atomicAdd(&agg[128 + m * 192 + 64 + lane], P10[m]);
                atomicAdd(&agg[128 + m * 192 + 128 + lane], P11[m]);
            }
        }
        __syncthreads();                                          // B4
    }

    // ---- P5 for all 4 nodes. Overlays: A-tiles over s_u, cout over rbf ----
    short* l0a    = (short*)s_u;              // 16x136 (rows 0-3 valid)
    short* l1a    = (short*)(s_u + 4352);     // 16x200 (rows 0-11 valid)
    short* g0t    = (short*)(s_u + 10752);    // 16x72 (rows 0-3 valid)
    short* g1t    = (short*)(s_u + 13056);    // 16x72 (rows 0-11 valid)
    float* s_cout = (float*)s_rr;             // 4x256 fp32 (4096 <= 5120)

    // pack agg -> bf16 A tiles
    #pragma unroll
    for (int rep = 0; rep < 2; ++rep) {
        int idx = t + rep * 256;              // 512 = 4 nodes x 128
        int n = idx >> 7, c = idx & 127;
        l0a[n * 136 + c] = f2bf(s_agg[n * 704 + c]);
    }
    for (int idx = t; idx < 2304; idx += 256) {  // 12 rows x 192
        int row = idx / 192, c = idx - row * 192;
        int node = (int)((unsigned)row / 3u);
        int m = row - node * 3;
        l1a[row * 200 + c] = f2bf(s_agg[node * 704 + 128 + m * 192 + c]);
    }
    __syncthreads();                                              // B5

    int col = 16 * wave + nn;
    // P5a: cout = ielin(agg, w_a) via MFMA
    {
        f32x4 acc0 = {0.f, 0.f, 0.f, 0.f};
        #pragma unroll
        for (int kc = 0; kc < 4; ++kc) {
            short8 b = *(const short8*)&w_a0t[col * 128 + kc * 32 + q * 8];
            short8 a = *(const short8*)&l0a[nn * 136 + kc * 32 + q * 8];
            acc0 = __builtin_amdgcn_mfma_f32_16x16x32_bf16(a, b, acc0, 0, 0, 0);
        }
        if (q == 0) {
            #pragma unroll
            for (int r = 0; r < 4; ++r)
                s_cout[r * 256 + col] = acc0[r];     // row r = node r
        }
        f32x4 acc1 = {0.f, 0.f, 0.f, 0.f};
        #pragma unroll
        for (int kc = 0; kc < 6; ++kc) {
            short8 b = *(const short8*)&w_a1t[col * 192 + kc * 32 + q * 8];
            short8 a = *(const short8*)&l1a[nn * 200 + kc * 32 + q * 8];
            acc1 = __builtin_amdgcn_mfma_f32_16x16x32_bf16(a, b, acc1, 0, 0, 0);
        }
        #pragma unroll
        for (int r = 0; r < 4; ++r) {
            int row = 4 * q + r;
            if (row < 12) {
                int node = (int)((unsigned)row / 3u);
                int m = row - node * 3;
                s_cout[node * 256 + 64 + m * 64 + col] = acc1[r];
            }
        }
    }
    __syncthreads();                                              // B6

    // gate -> bf16 gated A-tiles
    #pragma unroll
    for (int n = 0; n < 4; ++n) {
        float v = s_cout[n * 256 + t];
        float g;
        if (wave == 0) {
            g = ssp_fast(v);
        } else {
            float c0 = s_cout[n * 256 + 64 + lane];
            float c1 = s_cout[n * 256 + 128 + lane];
            float c2 = s_cout[n * 256 + 192 + lane];
            g = ssp_fast(sqrtf(fmaf(c0, c0, fmaf(c1, c1, fmaf(c2, c2, 1e-12f)))));
        }
        float gv = v * g;
        if (wave == 0) g0t[n * 72 + lane] = f2bf(gv);
        else           g1t[(n * 3 + wave - 1) * 72 + lane] = f2bf(gv);
    }
    __syncthreads();                                              // B7

    // P5b: out = feat + ielin(gated, w_b) via MFMA
    {
        f32x4 acc0 = {0.f, 0.f, 0.f, 0.f};
        #pragma unroll
        for (int kc = 0; kc < 2; ++kc) {
            short8 b = *(const short8*)&w_b0t[col * 64 + kc * 32 + q * 8];
            short8 a = *(const short8*)&g0t[nn * 72 + kc * 32 + q * 8];
            acc0 = __builtin_amdgcn_mfma_f32_16x16x32_bf16(a, b, acc0, 0, 0, 0);
        }
        if (q == 0) {
            #pragma unroll
            for (int r = 0; r < 4; ++r) {
                size_t o = (size_t)(i0 + r) * 256 + col;
                out[o] = feat[o] + acc0[r];
            }
        }
        f32x4 acc1 = {0.f, 0.f, 0.f, 0.f};
        #pragma unroll
        for (int kc = 0; kc < 2; ++kc) {
            short8 b = *(const short8*)&w_b1t[col * 64 + kc * 32 + q * 8];
            short8 a = *(const short8*)&g1t[nn * 72 + kc * 32 + q * 8];
            acc1 = __builtin_amdgcn_mfma_f32_16x16x32_bf16(a, b, acc1, 0, 0, 0);
        }
        #pragma unroll
        for (int r = 0; r < 4; ++r) {
            int row = 4 * q + r;
            if (row < 12) {
                int node = (int)((unsigned)row / 3u);
                int m = row - node * 3;
                size_t o = (size_t)(i0 + node) * 256 + 64 + m * 64 + col;
                out[o] = feat[o] + acc1[r];
            }
        }
    }
}

extern "C" void kernel_launch(void* const* d_in, const int* in_sizes, int n_in,
                              void* d_out, int out_size, void* d_ws, size_t ws_size,
                              hipStream_t stream) {
    const float* xyz     = (const float*)d_in[0];
    const float* feat    = (const float*)d_in[1];
    const float* w_f1    = (const float*)d_in[2];
    const float* w_f2    = (const float*)d_in[3];
    const float* w_pre0  = (const float*)d_in[4];
    const float* w_pre1  = (const float*)d_in[5];
    const float* w_a0    = (const float*)d_in[6];
    const float* w_a1    = (const float*)d_in[7];
    const float* w_b0    = (const float*)d_in[8];
    const float* w_b1    = (const float*)d_in[9];
    const int* src_idx   = (const int*)d_in[10];
    const int* edge_mask = (const int*)d_in[11];
    float* out = (float*)d_out;

    char* ws = (char*)d_ws;
    float* pre_t = (float*)ws;                          // 4 MB
    short* w1t   = (short*)(ws + 4194304);              // 4 KB
    short* w2t   = (short*)(ws + 4194304 + 4096);       // 8 KB
    short* w_a0t = (short*)(ws + 4194304 + 12288);      // 16 KB
    short* w_a1t = (short*)(ws + 4194304 + 28672);      // 24 KB
    short* w_b0t = (short*)(ws + 4194304 + 53248);      // 8 KB
    short* w_b1t = (short*)(ws + 4194304 + 61440);      // 8 KB

    pre_kernel<<<NN / 8, 256, 0, stream>>>(feat, w_pre0, w_pre1, pre_t,
                                           w_f1, w_f2, w_a0, w_a1, w_b0, w_b1,
                                           w1t, w2t, w_a0t, w_a1t, w_b0t, w_b1t);
    edge_kernel<<<NN / 4, 256, 0, stream>>>(xyz, feat, pre_t, w1t, w2t,
                                            w_a0t, w_a1t, w_b0t, w_b1t,
                                            src_idx, edge_mask, out);
}

// Round 14
// 107.818 us; speedup vs baseline: 1.5077x; 1.2606x over previous
//
#include <hip/hip_runtime.h>
#include <math.h>

#define NN 4096
#define MM 32
#define LOG2F_ 0.69314718055994530942f

typedef __attribute__((ext_vector_type(8))) short short8;
typedef __attribute__((ext_vector_type(4))) float f32x4;

__device__ __forceinline__ float ssp_fast(float x) {
    float sp = (x > 20.0f) ? x : __logf(1.0f + __expf(x));
    return sp - LOG2F_;
}

// float -> bf16 bits, round-to-nearest-even
__device__ __forceinline__ short f2bf(float x) {
    unsigned u = __float_as_uint(x);
    unsigned r = (u + 0x7FFFu + ((u >> 16) & 1u)) >> 16;
    return (short)r;
}
__device__ __forceinline__ float bf2f(short s) {
    return __uint_as_float(((unsigned)(unsigned short)s) << 16);
}

// K1: pre = ielin(feat, w_pre0, w_pre1) via MFMA, 8 nodes/block.
// Weight->bf16^T conversion spread across all blocks (<=1 elem/thread).
__global__ __launch_bounds__(256) void pre_kernel(
    const float* __restrict__ feat, const float* __restrict__ w0,
    const float* __restrict__ w1, float* __restrict__ pre_t,
    const float* __restrict__ w_f1, const float* __restrict__ w_f2,
    const float* __restrict__ w_a0, const float* __restrict__ w_a1,
    const float* __restrict__ w_b0, const float* __restrict__ w_b1,
    short* __restrict__ w1t, short* __restrict__ w2t,
    short* __restrict__ w_a0t, short* __restrict__ w_a1t,
    short* __restrict__ w_b0t, short* __restrict__ w_b1t)
{
    int t = threadIdx.x;
    int base = blockIdx.x * 8;
    int lane = t & 63, wave = t >> 6, q = lane >> 4, nn = lane & 15;

    // distributed weight transpose+convert: gid in [0, 34816)
    {
        int gid = blockIdx.x * 256 + t;
        if (gid < 2048) {
            int n = gid >> 5, k = gid & 31;
            w1t[gid] = (k < 16) ? f2bf(w_f1[k * 64 + n]) : (short)0;
        } else if (gid < 6144) {
            int idx = gid - 2048; int n = idx >> 6, k = idx & 63;
            w2t[idx] = f2bf(w_f2[k * 64 + n]);
        } else if (gid < 10240) {
            int idx = gid - 6144; int n = idx >> 6, k = idx & 63;
            w_b0t[idx] = f2bf(w_b0[k * 64 + n]);
        } else if (gid < 14336) {
            int idx = gid - 10240; int n = idx >> 6, k = idx & 63;
            w_b1t[idx] = f2bf(w_b1[k * 64 + n]);
        } else if (gid < 22528) {
            int idx = gid - 14336; int n = idx >> 7, k = idx & 127;
            w_a0t[idx] = f2bf(w_a0[k * 64 + n]);
        } else if (gid < 34816) {
            int idx = gid - 22528; int n = idx / 192, k = idx - n * 192;
            w_a1t[idx] = f2bf(w_a1[k * 64 + n]);
        }
    }

    __shared__ __align__(16) short s_a0[16 * 72];
    __shared__ __align__(16) short s_a1[2][16 * 72];
    __shared__ __align__(16) short s_w0[64 * 72];
    __shared__ __align__(16) short s_w1[64 * 72];
    __shared__ __align__(16) float s_po[8][256];

    for (int idx = t; idx < 512; idx += 256) {
        int r = 8 + (idx >> 6), k = idx & 63;
        s_a0[r * 72 + k] = 0;
        s_a1[1][r * 72 + k] = 0;
    }
    #pragma unroll 4
    for (int kk = 0; kk < 16; ++kk) {
        int k = wave * 16 + kk;
        s_w0[lane * 72 + k] = f2bf(w0[k * 64 + lane]);
        s_w1[lane * 72 + k] = f2bf(w1[k * 64 + lane]);
    }
    {
        const float4* f4 = (const float4*)(feat + (size_t)base * 256);
        #pragma unroll
        for (int rep = 0; rep < 2; ++rep) {
            int idx = t + rep * 256;
            float4 v = f4[idx];
            int node = idx >> 6, c = (idx & 63) * 4;
            short* dst;
            if (c < 64) {
                dst = &s_a0[node * 72 + c];
            } else {
                int mm = (c >> 6) - 1, ch = c & 63;
                int row = node * 3 + mm;
                dst = &s_a1[row >> 4][(row & 15) * 72 + ch];
            }
            dst[0] = f2bf(v.x); dst[1] = f2bf(v.y);
            dst[2] = f2bf(v.z); dst[3] = f2bf(v.w);
        }
    }
    __syncthreads();

    short8 bw0[2], bw1[2];
    #pragma unroll
    for (int kc = 0; kc < 2; ++kc) {
        bw0[kc] = *(const short8*)&s_w0[(16 * wave + nn) * 72 + kc * 32 + q * 8];
        bw1[kc] = *(const short8*)&s_w1[(16 * wave + nn) * 72 + kc * 32 + q * 8];
    }
    {
        f32x4 acc = {0.f, 0.f, 0.f, 0.f};
        #pragma unroll
        for (int kc = 0; kc < 2; ++kc) {
            short8 a = *(const short8*)&s_a0[nn * 72 + kc * 32 + q * 8];
            acc = __builtin_amdgcn_mfma_f32_16x16x32_bf16(a, bw0[kc], acc, 0, 0, 0);
        }
        if (q < 2) {
            #pragma unroll
            for (int r = 0; r < 4; ++r)
                s_po[4 * q + r][(16 * wave + nn) * 4 + 0] = acc[r];
        }
    }
    #pragma unroll
    for (int tile = 0; tile < 2; ++tile) {
        f32x4 acc = {0.f, 0.f, 0.f, 0.f};
        #pragma unroll
        for (int kc = 0; kc < 2; ++kc) {
            short8 a = *(const short8*)&s_a1[tile][nn * 72 + kc * 32 + q * 8];
            acc = __builtin_amdgcn_mfma_f32_16x16x32_bf16(a, bw1[kc], acc, 0, 0, 0);
        }
        #pragma unroll
        for (int r = 0; r < 4; ++r) {
            int row = tile * 16 + 4 * q + r;
            if (row < 24) {
                unsigned node = (unsigned)row / 3u;
                int mm = row - (int)node * 3;
                s_po[node][(16 * wave + nn) * 4 + 1 + mm] = acc[r];
            }
        }
    }
    __syncthreads();

    #pragma unroll
    for (int rep = 0; rep < 2; ++rep) {
        int idx = t + rep * 256;
        int node = idx >> 6, c4 = idx & 63;
        *(float4*)&pre_t[(size_t)(base + node) * 256 + c4 * 4] =
            *(const float4*)&s_po[node][c4 * 4];
    }
}

// K2: WAVE-AUTONOMOUS. 4 nodes/block; each wave owns one node (32 edges)
// end-to-end with NO block barriers through the radial+coupling phases:
// rbf A-fragments in registers, h/f transposes in wave-private LDS, agg
// accumulated in registers (lane == channel). One barrier, then shared
// 4-node MFMA P5. 4 barriers total (was 8). LDS 36 KB -> 4 blocks/CU.
__global__ __launch_bounds__(256, 4) void edge_kernel(
    const float* __restrict__ xyz, const float* __restrict__ feat,
    const float* __restrict__ pre_t,
    const short* __restrict__ w1t_g, const short* __restrict__ w2t_g,
    const short* __restrict__ w_a0t, const short* __restrict__ w_a1t,
    const short* __restrict__ w_b0t, const short* __restrict__ w_b1t,
    const int* __restrict__ src_idx, const int* __restrict__ edge_mask,
    float* __restrict__ out)
{
    int i0 = blockIdx.x * 4;
    int t = threadIdx.x;
    int lane = t & 63;
    int wave = t >> 6;
    int q = lane >> 4;
    int nn = lane & 15;

    __shared__ __align__(16) char s_u[36864];   // 4 x 9216 wave-private; P5 overlays
    short* s_h = (short*)(s_u + wave * 9216);           // 32 x 72 bf16
    short* s_f = (short*)(s_u + wave * 9216 + 4608);    // 32 x 72 bf16

    int node = i0 + wave;

    // ---- geometry: lane handles edge lane&31 (2-way redundant) ----
    int e = lane & 31;
    int j = src_idx[node * MM + e];
    float msk = (float)edge_mask[node * MM + e];
    float r0 = xyz[j * 3 + 0] - xyz[node * 3 + 0];
    float r1 = xyz[j * 3 + 1] - xyz[node * 3 + 1];
    float r2 = xyz[j * 3 + 2] - xyz[node * 3 + 2];
    float d = sqrtf(r0 * r0 + r1 * r1 + r2 * r2);
    float inv_d = 1.0f / d;
    float x = d * 0.2f;
    float env = 0.f;
    if (x < 1.f) {
        float x3 = x * x * x;
        env = 1.f - 10.f * x3 + 15.f * x3 * x - 6.f * x3 * x * x;
    }
    float sc = env * inv_d;
    float ry = r1 * inv_d, rz = r2 * inv_d, rx = r0 * inv_d;

    // ---- prefetch gather groups 0,1 (edges 0-7) ----
    float4 pv[2][4];
    #pragma unroll
    for (int u = 0; u < 4; ++u) {
        int ju = __shfl(j, u, 64);
        pv[0][u] = ((const float4*)pre_t)[(size_t)ju * 64 + lane];
    }
    #pragma unroll
    for (int u = 0; u < 4; ++u) {
        int ju = __shfl(j, 4 + u, 64);
        pv[1][u] = ((const float4*)pre_t)[(size_t)ju * 64 + lane];
    }

    // ---- rbf A-fragments in registers ----
    // A[m=edge(mt*16+nn)][k=q*8+jj]; k>=16 zero (w1t pad rows are zero too,
    // but registers must be finite -> explicit zeros).
    short8 a_frag[2];
    #pragma unroll
    for (int mt = 0; mt < 2; ++mt) {
        float xe  = __shfl(x,  mt * 16 + nn, 64);
        float sce = __shfl(sc, mt * 16 + nn, 64);
        short8 af = {0, 0, 0, 0, 0, 0, 0, 0};
        if (q < 2) {
            #pragma unroll
            for (int jj = 0; jj < 8; ++jj) {
                float kf = (float)(q * 8 + jj);
                af[jj] = f2bf(__sinf(xe * kf) * sce);
            }
        }
        a_frag[mt] = af;
    }

    // ---- P2: h = ssp(rbf @ w1); wave covers all 64 hidden cols ----
    {
        f32x4 z = {0.f, 0.f, 0.f, 0.f};
        #pragma unroll
        for (int nt = 0; nt < 4; ++nt) {
            short8 b = *(const short8*)&w1t_g[(16 * nt + nn) * 32 + q * 8];
            #pragma unroll
            for (int mt = 0; mt < 2; ++mt) {
                f32x4 h = __builtin_amdgcn_mfma_f32_16x16x32_bf16(a_frag[mt], b, z, 0, 0, 0);
                #pragma unroll
                for (int r = 0; r < 4; ++r)
                    s_h[(16 * mt + 4 * q + r) * 72 + 16 * nt + nn] = f2bf(ssp_fast(h[r]));
            }
        }
    }

    // ---- P3: fr = h @ w2 (wave-private; intra-wave lgkmcnt ordering) ----
    {
        #pragma unroll
        for (int nt = 0; nt < 4; ++nt) {
            f32x4 acc[2];
            acc[0] = (f32x4){0.f, 0.f, 0.f, 0.f};
            acc[1] = (f32x4){0.f, 0.f, 0.f, 0.f};
            #pragma unroll
            for (int kc = 0; kc < 2; ++kc) {
                short8 b = *(const short8*)&w2t_g[(16 * nt + nn) * 64 + kc * 32 + q * 8];
                #pragma unroll
                for (int mt = 0; mt < 2; ++mt) {
                    short8 a = *(const short8*)&s_h[(16 * mt + nn) * 72 + kc * 32 + q * 8];
                    acc[mt] = __builtin_amdgcn_mfma_f32_16x16x32_bf16(a, b, acc[mt], 0, 0, 0);
                }
            }
            #pragma unroll
            for (int mt = 0; mt < 2; ++mt)
                #pragma unroll
                for (int r = 0; r < 4; ++r)
                    s_f[(16 * mt + 4 * q + r) * 72 + 16 * nt + nn] = f2bf(acc[mt][r]);
        }
    }

    // ---- P4: coupling over the wave's 32 edges; agg in REGISTERS ----
    float acc0a = 0.f, acc0b = 0.f;
    float P01[3] = {0.f, 0.f, 0.f};
    float P10[3] = {0.f, 0.f, 0.f};
    float P11[3] = {0.f, 0.f, 0.f};
    {
        #pragma unroll
        for (int g = 0; g < 8; ++g) {
            int cur = g & 1;
            #pragma unroll
            for (int u = 0; u < 4; ++u) {
                int el = g * 4 + u;
                float ryu = __shfl(ry, el, 64);
                float rzu = __shfl(rz, el, 64);
                float rxu = __shfl(rx, el, 64);
                float msku = __shfl(msk, el, 64);
                float f = bf2f(s_f[el * 72 + lane]) * msku;
                float a0 = pv[cur][u].x, a1y = pv[cur][u].y;
                float a1z = pv[cur][u].z, a1x = pv[cur][u].w;

                float a0f = a0 * f;
                acc0a += a0f;
                acc0b = fmaf(f, a1y * ryu + a1z * rzu + a1x * rxu, acc0b);
                P01[0] = fmaf(a0f, ryu, P01[0]);
                P01[1] = fmaf(a0f, rzu, P01[1]);
                P01[2] = fmaf(a0f, rxu, P01[2]);
                P10[0] = fmaf(a1y, f, P10[0]);
                P10[1] = fmaf(a1z, f, P10[1]);
                P10[2] = fmaf(a1x, f, P10[2]);
                P11[0] = fmaf(a1z * rxu - a1x * rzu, f, P11[0]);  // cy
                P11[1] = fmaf(a1x * ryu - a1y * rxu, f, P11[1]);  // cz
                P11[2] = fmaf(a1y * rzu - a1z * ryu, f, P11[2]);  // cx
            }
            if (g < 6) {   // prefetch group g+2 into the buffer just freed
                #pragma unroll
                for (int u = 0; u < 4; ++u) {
                    int jn = __shfl(j, (g + 2) * 4 + u, 64);
                    pv[cur][u] = ((const float4*)pre_t)[(size_t)jn * 64 + lane];
                }
            }
        }
    }
    __syncthreads();                                              // B1

    // ---- P5 overlays (all waves' h/f dead) ----
    short* l0a    = (short*)s_u;               // 16x136 (rows 0-3 valid)
    short* l1a    = (short*)(s_u + 4352);      // 16x200 (rows 0-11 valid)
    short* g0t    = (short*)(s_u + 10752);     // 16x72 (rows 0-3 valid)
    short* g1t    = (short*)(s_u + 13056);     // 16x72 (rows 0-11 valid)
    float* s_cout = (float*)(s_u + 15360);     // 4x256 fp32

    // pack agg (registers) -> bf16 A tiles; lane == channel
    l0a[wave * 136 + lane]      = f2bf(acc0a);
    l0a[wave * 136 + 64 + lane] = f2bf(acc0b);
    #pragma unroll
    for (int m = 0; m < 3; ++m) {
        short* row = &l1a[(wave * 3 + m) * 200];
        row[lane]       = f2bf(P01[m]);
        row[64 + lane]  = f2bf(P10[m]);
        row[128 + lane] = f2bf(P11[m]);
    }
    __syncthreads();                                              // B2

    int col = 16 * wave + nn;
    // P5a: cout = ielin(agg, w_a) via MFMA
    {
        f32x4 acc0 = {0.f, 0.f, 0.f, 0.f};
        #pragma unroll
        for (int kc = 0; kc < 4; ++kc) {
            short8 b = *(const short8*)&w_a0t[col * 128 + kc * 32 + q * 8];
            short8 a = *(const short8*)&l0a[nn * 136 + kc * 32 + q * 8];
            acc0 = __builtin_amdgcn_mfma_f32_16x16x32_bf16(a, b, acc0, 0, 0, 0);
        }
        if (q == 0) {
            #pragma unroll
            for (int r = 0; r < 4; ++r)
                s_cout[r * 256 + col] = acc0[r];     // row r = node r
        }
        f32x4 acc1 = {0.f, 0.f, 0.f, 0.f};
        #pragma unroll
        for (int kc = 0; kc < 6; ++kc) {
            short8 b = *(const short8*)&w_a1t[col * 192 + kc * 32 + q * 8];
            short8 a = *(const short8*)&l1a[nn * 200 + kc * 32 + q * 8];
            acc1 = __builtin_amdgcn_mfma_f32_16x16x32_bf16(a, b, acc1, 0, 0, 0);
        }
        #pragma unroll
        for (int r = 0; r < 4; ++r) {
            int row = 4 * q + r;
            if (row < 12) {
                int nd = (int)((unsigned)row / 3u);
                int m = row - nd * 3;
                s_cout[nd * 256 + 64 + m * 64 + col] = acc1[r];
            }
        }
    }
    __syncthreads();                                              // B3

    // gate -> bf16 gated A-tiles
    #pragma unroll
    for (int n = 0; n < 4; ++n) {
        float v = s_cout[n * 256 + t];
        float g;
        if (wave == 0) {
            g = ssp_fast(v);
        } else {
            float c0 = s_cout[n * 256 + 64 + lane];
            float c1 = s_cout[n * 256 + 128 + lane];
            float c2 = s_cout[n * 256 + 192 + lane];
            g = ssp_fast(sqrtf(fmaf(c0, c0, fmaf(c1, c1, fmaf(c2, c2, 1e-12f)))));
        }
        float gv = v * g;
        if (wave == 0) g0t[n * 72 + lane] = f2bf(gv);
        else           g1t[(n * 3 + wave - 1) * 72 + lane] = f2bf(gv);
    }
    __syncthreads();                                              // B4

    // P5b: out = feat + ielin(gated, w_b) via MFMA
    {
        f32x4 acc0 = {0.f, 0.f, 0.f, 0.f};
        #pragma unroll
        for (int kc = 0; kc < 2; ++kc) {
            short8 b = *(const short8*)&w_b0t[col * 64 + kc * 32 + q * 8];
            short8 a = *(const short8*)&g0t[nn * 72 + kc * 32 + q * 8];
            acc0 = __builtin_amdgcn_mfma_f32_16x16x32_bf16(a, b, acc0, 0, 0, 0);
        }
        if (q == 0) {
            #pragma unroll
            for (int r = 0; r < 4; ++r) {
                size_t o = (size_t)(i0 + r) * 256 + col;
                out[o] = feat[o] + acc0[r];
            }
        }
        f32x4 acc1 = {0.f, 0.f, 0.f, 0.f};
        #pragma unroll
        for (int kc = 0; kc < 2; ++kc) {
            short8 b = *(const short8*)&w_b1t[col * 64 + kc * 32 + q * 8];
            short8 a = *(const short8*)&g1t[nn * 72 + kc * 32 + q * 8];
            acc1 = __builtin_amdgcn_mfma_f32_16x16x32_bf16(a, b, acc1, 0, 0, 0);
        }
        #pragma unroll
        for (int r = 0; r < 4; ++r) {
            int row = 4 * q + r;
            if (row < 12) {
                int nd = (int)((unsigned)row / 3u);
                int m = row - nd * 3;
                size_t o = (size_t)(i0 + nd) * 256 + 64 + m * 64 + col;
                out[o] = feat[o] + acc1[r];
            }
        }
    }
}

extern "C" void kernel_launch(void* const* d_in, const int* in_sizes, int n_in,
                              void* d_out, int out_size, void* d_ws, size_t ws_size,
                              hipStream_t stream) {
    const float* xyz     = (const float*)d_in[0];
    const float* feat    = (const float*)d_in[1];
    const float* w_f1    = (const float*)d_in[2];
    const float* w_f2    = (const float*)d_in[3];
    const float* w_pre0  = (const float*)d_in[4];
    const float* w_pre1  = (const float*)d_in[5];
    const float* w_a0    = (const float*)d_in[6];
    const float* w_a1    = (const float*)d_in[7];
    const float* w_b0    = (const float*)d_in[8];
    const float* w_b1    = (const float*)d_in[9];
    const int* src_idx   = (const int*)d_in[10];
    const int* edge_mask = (const int*)d_in[11];
    float* out = (float*)d_out;

    char* ws = (char*)d_ws;
    float* pre_t = (float*)ws;                          // 4 MB
    short* w1t   = (short*)(ws + 4194304);              // 4 KB
    short* w2t   = (short*)(ws + 4194304 + 4096);       // 8 KB
    short* w_a0t = (short*)(ws + 4194304 + 12288);      // 16 KB
    short* w_a1t = (short*)(ws + 4194304 + 28672);      // 24 KB
    short* w_b0t = (short*)(ws + 4194304 + 53248);      // 8 KB
    short* w_b1t = (short*)(ws + 4194304 + 61440);      // 8 KB

    pre_kernel<<<NN / 8, 256, 0, stream>>>(feat, w_pre0, w_pre1, pre_t,
                                           w_f1, w_f2, w_a0, w_a1, w_b0, w_b1,
                                           w1t, w2t, w_a0t, w_a1t, w_b0t, w_b1t);
    edge_kernel<<<NN / 4, 256, 0, stream>>>(xyz, feat, pre_t, w1t, w2t,
                                            w_a0t, w_a1t, w_b0t, w_b1t,
                                            src_idx, edge_mask, out);
}